// Round 6
// baseline (301.526 us; speedup 1.0000x reference)
//
#include <hip/hip_runtime.h>
#include <hip/hip_bf16.h>

// FastCMIF: sliding-window mutual information via exact integer joint
// histograms (replaces the reference's 256 FFT convolutions).
//
// MI = (1/N)[ sum c_kl ln c_kl - sum c_k ln c_k - sum c_l ln c_l + N ln N ]
// OOB window pixels add 0 (border blocks), reproducing border clip + mask.
//
// R6: k_main is at the LDS-atomic-pipe wall (measured 14.5 cyc per 64-lane
// ds_add across 3 different occupancies/code shapes; 10.6M wave-atomics
// x 14.5 cyc / 256 CU / 2.4 GHz = 250 us = measured). This round shaves the
// ~48 us of non-k_main time: min/max fused into ONE kernel via global
// atomicMin/Max on monotone u32 float keys (init by 2 hipMemsetAsync).

#define IMH 384
#define IMW 384
#define TH 48
#define TW 48
#define PAD 24
#define PH 432
#define PIMG (PH*PH)        // 186624
#define NIMGW (PIMG/4)      // 46656 words
#define TOTW (2*NIMGW)      // 93312
#define FLTMAX 3.402823466e+38f

#if __has_builtin(__builtin_amdgcn_alignbyte)
#define ALIGNBYTE(hi,lo,s) __builtin_amdgcn_alignbyte((hi),(lo),(s))
#else
#define ALIGNBYTE(hi,lo,s) ((unsigned)(((((unsigned long long)(hi))<<32)|(unsigned long long)(lo)) >> ((s)*8)))
#endif

// monotone float<->u32 key mapping (works for any sign)
__device__ __forceinline__ unsigned enkey(float f) {
    unsigned u = __float_as_uint(f);
    return u ^ ((unsigned)(((int)u) >> 31) | 0x80000000u);
}
__device__ __forceinline__ float dekey(unsigned k) {
    unsigned u = (k & 0x80000000u) ? (k ^ 0x80000000u) : ~k;
    return __uint_as_float(u);
}

// ---- fused min/max: 68 blocks, local reduce + global atomicMin/Max ----
// keys layout: [0..3] = min keys (im0,im1,t0,t1) init 0xFF; [4..7] = max keys init 0x00
__global__ void k_mm(const float* __restrict__ im, const float* __restrict__ tm,
                     unsigned* __restrict__ keys) {
    int b = blockIdx.x;
    const float* src;
    int base, cnt, seg;
    if (b < 64) { src = im + (b >> 5) * (IMH*IMW); base = (b & 31) * 4608; cnt = 4608; seg = b >> 5; }
    else        { src = tm + ((b - 64) >> 1) * (TH*TW); base = ((b - 64) & 1) * 1152; cnt = 1152; seg = 2 + ((b - 64) >> 1); }
    float mn0 = FLTMAX, mx0 = -FLTMAX, mn1 = FLTMAX, mx1 = -FLTMAX;
    for (int i = threadIdx.x; i < cnt; i += 512) {
        float v = src[base + i];
        mn0 = fminf(mn0, v); mx0 = fmaxf(mx0, v);
        if (i + 256 < cnt) {
            float w = src[base + i + 256];
            mn1 = fminf(mn1, w); mx1 = fmaxf(mx1, w);
        }
    }
    float mn = fminf(mn0, mn1), mx = fmaxf(mx0, mx1);
    for (int o = 32; o > 0; o >>= 1) {
        mn = fminf(mn, __shfl_down(mn, o));
        mx = fmaxf(mx, __shfl_down(mx, o));
    }
    __shared__ float smn[4], smx[4];
    int w = threadIdx.x >> 6;
    if ((threadIdx.x & 63) == 0) { smn[w] = mn; smx[w] = mx; }
    __syncthreads();
    if (threadIdx.x == 0) {
        mn = fminf(fminf(smn[0], smn[1]), fminf(smn[2], smn[3]));
        mx = fmaxf(fmaxf(smx[0], smx[1]), fmaxf(smx[2], smx[3]));
        atomicMin(&keys[seg],     enkey(mn));
        atomicMax(&keys[4 + seg], enkey(mx));
    }
}

// Fused bin+pad and template pack.
__global__ void k_prep(const float* __restrict__ im, const float* __restrict__ tm,
                       const unsigned* __restrict__ keys,
                       unsigned* __restrict__ pImW, unsigned* __restrict__ pT) {
    int blk = blockIdx.x;
    if (blk < 365) {
        int wi = blk * 256 + threadIdx.x;
        if (wi >= TOTW) return;
        int b = wi / NIMGW;
        int rem4 = (wi - b * NIMGW) * 4;
        int py = rem4 / PH;
        int px = rem4 - py * PH;
        float mn = dekey(keys[b]), mx = dekey(keys[4 + b]);
        unsigned word = 0;
        #pragma unroll
        for (int j = 0; j < 4; ++j) {
            int x = px + j;
            unsigned bin = 16u;              // sentinel: outside image
            if (py >= PAD && py < PAD + IMH && x >= PAD && x < PAD + IMW) {
                float v = im[b * (IMH*IMW) + (py - PAD) * IMW + (x - PAD)];
                // replicate reference numerics exactly: sub, IEEE div, mul 15, floor
                float r = (v - mn) / (mx - mn);
                bin = (unsigned)(int)floorf(r * 15.0f);
            }
            word |= bin << (8*j);
        }
        pImW[wi] = word;
    } else {
        for (int t = threadIdx.x; t < 576; t += 256) {
            int b = t / 288, w = t - b * 288;
            float mn = dekey(keys[2 + b]), mx = dekey(keys[6 + b]);
            const float* tptr = tm + b * (TH*TW) + w * 8;
            unsigned word = 0;
            #pragma unroll
            for (int j = 0; j < 8; ++j) {
                float r = (tptr[j] - mn) / (mx - mn);
                word |= ((unsigned)(int)floorf(r * 15.0f)) << (4*j);
            }
            pT[b*288 + w] = word;
        }
    }
}

__device__ __forceinline__ void load_row(const uint2* rowp, int r, unsigned (&w)[14]) {
    const uint2* p = rowp + r * (PH / 8);
    #pragma unroll
    for (int i = 0; i < 7; ++i) { uint2 v = p[i]; w[2*i] = v.x; w[2*i+1] = v.y; }
}
__device__ __forceinline__ void load_t(const uint2* tp, int r, unsigned (&t)[6]) {
    const uint2* p = tp + r * 3;
    #pragma unroll
    for (int i = 0; i < 3; ++i) { uint2 v = p[i]; t[2*i] = v.x; t[2*i+1] = v.y; }
}

// One window row: 48 updates, no convergent ops inside the loop.
template<bool BORDER>
__device__ __forceinline__ void do_row(const unsigned (&w)[14], const unsigned (&t)[6],
                                       unsigned* __restrict__ hist, int tid,
                                       unsigned sh, bool sel) {
    unsigned wsel[13];
    #pragma unroll
    for (int i = 0; i < 13; ++i) wsel[i] = sel ? w[i+1] : w[i];
    unsigned a[12];   // a[i] bytes = image bins at window cols 4i..4i+3
    #pragma unroll
    for (int i = 0; i < 12; ++i) a[i] = ALIGNBYTE(wsel[i+1], wsel[i], sh);
    unsigned tq[6];   // once per row: SGPR-ize the (uniform) template words
    #pragma unroll
    for (int j = 0; j < 6; ++j)
        tq[j] = (unsigned)__builtin_amdgcn_readfirstlane((int)t[j]);

    #pragma unroll
    for (int c = 0; c < 48; ++c) {
        unsigned byteval = (a[c >> 2] >> ((c & 3) * 8)) & 0xFFu;  // VALU (v_bfe)
        unsigned l    = (tq[c >> 3] >> ((c & 7) * 4)) & 0xFu;     // SALU (tq uniform)
        unsigned soff = (l >> 2) << 6;                            // SALU
        unsigned sadd = 1u << ((l & 3u) << 3);                    // SALU
        if (BORDER) {
            unsigned bin   = byteval & 15u;
            unsigned adder = (byteval != 16u) ? sadd : 0u;        // v_cmp + cndmask
            atomicAdd(&hist[(bin << 8) + soff + tid], adder);
        } else {
            atomicAdd(&hist[(byteval << 8) + soff + tid], sadd);  // lshl+add3+mov+ds_add
        }
    }
}

template<bool BORDER>
__device__ __forceinline__ void accum_tile(const uint2* rowp, const uint2* tp,
                                           unsigned* __restrict__ hist, int tid,
                                           unsigned sh, bool sel) {
    unsigned w0[14], w1[14], t0[6], t1[6];
    load_row(rowp, 0, w0); load_t(tp, 0, t0);
    #pragma unroll 1
    for (int r = 0; r < 48; r += 2) {
        load_row(rowp, r + 1, w1); load_t(tp, r + 1, t1);   // r+1 <= 47 always
        do_row<BORDER>(w0, t0, hist, tid, sh, sel);
        if (r + 2 < 48) { load_row(rowp, r + 2, w0); load_t(tp, r + 2, t0); }
        do_row<BORDER>(w1, t1, hist, tid, sh, sel);
    }
}

__global__ __launch_bounds__(64, 4)
void k_main(const unsigned char* __restrict__ pIm, const unsigned* __restrict__ pT,
            float* __restrict__ out) {
    // u8-packed per-lane joint histograms: word = (bin*4 + l/4)*64 + tid,
    // byte = l&3. 16 * 4 * 64 u32 = 16384 B -> up to 10 blocks/CU.
    __shared__ unsigned hist[16 * 4 * 64];
    const int tid = threadIdx.x;
    const int tx = tid & 7, ty = tid >> 3;
    const int b = blockIdx.z;
    const int X0 = blockIdx.x << 3, Y0 = blockIdx.y << 3;

    {   // zero; lane stride 4 words
        uint4 z = {0u, 0u, 0u, 0u};
        #pragma unroll
        for (int i = 0; i < 16; ++i) ((uint4*)hist)[i * 64 + tid] = z;
    }
    __syncthreads();

    const uint2* rowp = (const uint2*)(pIm + b * PIMG + (Y0 + ty) * PH + X0); // 8B-aligned
    const uint2* tp   = (const uint2*)(pT + b * 288);                          // 8B-aligned
    const unsigned sh = tx & 3;
    const bool sel = (tx & 4) != 0;

    // interior iff no touched padded col/row can be sentinel: [X0,X0+56) in [24,408)
    const bool interior = (blockIdx.x >= 3) && (blockIdx.x <= 43) &&
                          (blockIdx.y >= 3) && (blockIdx.y <= 43);
    if (interior) accum_tile<false>(rowp, tp, hist, tid, sh, sel);
    else          accum_tile<true >(rowp, tp, hist, tid, sh, sel);

    // epilogue: MI from own histogram
    float A = 0.0f;
    int coll[16];
    #pragma unroll
    for (int i = 0; i < 16; ++i) coll[i] = 0;
    int N = 0;
    #pragma unroll
    for (int k = 0; k < 16; ++k) {
        int rk = 0;
        #pragma unroll
        for (int q = 0; q < 4; ++q) {
            unsigned v = hist[(k << 8) + (q << 6) + tid];
            #pragma unroll
            for (int j = 0; j < 4; ++j) {
                int c = (int)((v >> (8*j)) & 0xFFu);
                rk += c;
                coll[(q << 2) + j] += c;
                if (c) A += (float)c * logf((float)c);
            }
        }
        if (rk) A -= (float)rk * logf((float)rk);
        N += rk;
    }
    #pragma unroll
    for (int i = 0; i < 16; ++i)
        if (coll[i]) A -= (float)coll[i] * logf((float)coll[i]);
    float fN = (float)N;
    out[(b * IMH + Y0 + ty) * IMW + X0 + tx] = (A + fN * logf(fN)) / fN;
}

extern "C" void kernel_launch(void* const* d_in, const int* in_sizes, int n_in,
                              void* d_out, int out_size, void* d_ws, size_t ws_size,
                              hipStream_t stream) {
    const float* im = (const float*)d_in[0];
    const float* tm = (const float*)d_in[1];
    float* out = (float*)d_out;
    unsigned char* pIm = (unsigned char*)d_ws;             // 373248 B
    unsigned* pT   = (unsigned*)((char*)d_ws + 373248);    // 2304 B
    unsigned* keys = (unsigned*)((char*)d_ws + 375552);    // 32 B (8 u32 keys)

    // init min keys to 0xFFFFFFFF, max keys to 0x00000000 (graph-capturable)
    hipMemsetAsync(keys,     0xFF, 16, stream);
    hipMemsetAsync(keys + 4, 0x00, 16, stream);
    k_mm<<<68, 256, 0, stream>>>(im, tm, keys);
    k_prep<<<366, 256, 0, stream>>>(im, tm, keys, (unsigned*)pIm, pT);
    k_main<<<dim3(48, 48, 2), 64, 0, stream>>>(pIm, pT, out);
}